// Round 4
// baseline (486.223 us; speedup 1.0000x reference)
//
#include <hip/hip_runtime.h>
#include <stdint.h>
#include <stddef.h>

#define DEV __device__ __forceinline__

typedef _Float16 f16x8 __attribute__((ext_vector_type(8)));
typedef float    f32x4 __attribute__((ext_vector_type(4)));
typedef int      i32x4 __attribute__((ext_vector_type(4)));

#define K2E 1.44269504088896340736f

DEV uint16_t f2h(float f) {
  _Float16 h = (_Float16)f;
  return __builtin_bit_cast(uint16_t, h);
}
DEV float h2f(uint16_t u) {
  return (float)__builtin_bit_cast(_Float16, u);
}
DEV f16x8 ldfrag(const uint16_t* p) {
  i32x4 v = *(const i32x4*)p;
  return __builtin_bit_cast(f16x8, v);
}
DEV f32x4 mfma16(f16x8 a, f16x8 b, f32x4 c) {
  return __builtin_amdgcn_mfma_f32_16x16x32_f16(a, b, c, 0, 0, 0);
}
// async global->LDS: each lane copies 16B; LDS dest = base + lane*16 (wave-uniform base)
DEV void gld_lds16(const uint16_t* g, uint16_t* l) {
  __builtin_amdgcn_global_load_lds(
      (__attribute__((address_space(1))) void*)g,
      (__attribute__((address_space(3))) void*)l, 16, 0, 0);
}

union U16x8 { uint16_t u[8]; i32x4 v; };

// ---------------- cast f32 -> f16 (8 elems/thread) ----------------
__global__ __launch_bounds__(256) void cast_f16_kernel(
    const float* __restrict__ in, uint16_t* __restrict__ outp, int n8) {
  int i = blockIdx.x * 256 + threadIdx.x;
  if (i >= n8) return;
  float4 a = *(const float4*)(in + (size_t)i * 8);
  float4 b = *(const float4*)(in + (size_t)i * 8 + 4);
  U16x8 r;
  r.u[0] = f2h(a.x); r.u[1] = f2h(a.y); r.u[2] = f2h(a.z); r.u[3] = f2h(a.w);
  r.u[4] = f2h(b.x); r.u[5] = f2h(b.y); r.u[6] = f2h(b.z); r.u[7] = f2h(b.w);
  *(i32x4*)(outp + (size_t)i * 8) = r.v;
}

// ---------------- transpose + cast: W[1024][ldw] f32 -> Wt[n][1024] f16 ----
__global__ __launch_bounds__(256) void transpose_cast_kernel(
    const float* __restrict__ W, uint16_t* __restrict__ Wt, int ldw) {
  __shared__ float tile[64][65];
  int k0 = blockIdx.x * 64;
  int n0 = blockIdx.y * 64;
  int tid = threadIdx.x;
#pragma unroll
  for (int i = 0; i < 16; ++i) {
    int flat = i * 256 + tid;
    int r = flat >> 6, c = flat & 63;
    tile[r][c] = W[(size_t)(k0 + r) * ldw + n0 + c];
  }
  __syncthreads();
#pragma unroll
  for (int i = 0; i < 16; ++i) {
    int flat = i * 256 + tid;
    int r = flat >> 6, c = flat & 63;
    Wt[(size_t)(n0 + r) * 1024 + k0 + c] = f2h(tile[c][r]);
  }
}

// ---------------- GEMM: C[M,N] = A[M,K] @ Bt[N,K]^T  (f16 in, f32 out) -----
// 128x128 tile, BK=64. global_load_lds width=16, unpadded tiles,
// XOR k-segment swizzle (LDS seg = gseg ^ (row&7)) -> frag reads <=2-way banks.
__global__ __launch_bounds__(256, 2) void gemm_bt_kernel(
    const uint16_t* __restrict__ A, const uint16_t* __restrict__ Bt,
    float* __restrict__ C, int N, int K, float scale) {
  __shared__ __align__(16) uint16_t As[128 * 64];
  __shared__ __align__(16) uint16_t Bs[128 * 64];
  int tid = threadIdx.x;
  int w = tid >> 6, lane = tid & 63, quad = lane >> 4, l15 = lane & 15;
  int wm = (w >> 1) * 64, wn = (w & 1) * 64;
  int bm = blockIdx.x, bn = blockIdx.y;
  const uint16_t* Arow = A + (size_t)(bm * 128) * K;
  const uint16_t* Brow = Bt + (size_t)(bn * 128) * K;
  f32x4 acc[4][4];
  f32x4 zero = {0.f, 0.f, 0.f, 0.f};
#pragma unroll
  for (int i = 0; i < 4; ++i)
#pragma unroll
    for (int j = 0; j < 4; ++j) acc[i][j] = zero;
  int rl = lane >> 3, cl = lane & 7;   // staging: 8 rows x 8 segs per wave-instr
  int sw = l15 & 7;                    // frag-read swizzle key
  for (int k0 = 0; k0 < K; k0 += 64) {
    __syncthreads();
#pragma unroll
    for (int t = 0; t < 4; ++t) {
      int r0 = w * 32 + t * 8;
      const uint16_t* ga = Arow + (size_t)(r0 + rl) * K + k0 + ((cl ^ rl) << 3);
      const uint16_t* gb = Brow + (size_t)(r0 + rl) * K + k0 + ((cl ^ rl) << 3);
      gld_lds16(ga, As + r0 * 64);
      gld_lds16(gb, Bs + r0 * 64);
    }
    __syncthreads();
#pragma unroll
    for (int ks = 0; ks < 2; ++ks) {
      f16x8 af[4], bf[4];
#pragma unroll
      for (int mt = 0; mt < 4; ++mt)
        af[mt] = ldfrag(As + (wm + mt * 16 + l15) * 64 + ((((ks << 2) + quad) ^ sw) << 3));
#pragma unroll
      for (int nt = 0; nt < 4; ++nt)
        bf[nt] = ldfrag(Bs + (wn + nt * 16 + l15) * 64 + ((((ks << 2) + quad) ^ sw) << 3));
#pragma unroll
      for (int mt = 0; mt < 4; ++mt)
#pragma unroll
        for (int nt = 0; nt < 4; ++nt)
          acc[mt][nt] = mfma16(af[mt], bf[nt], acc[mt][nt]);
    }
  }
#pragma unroll
  for (int mt = 0; mt < 4; ++mt)
#pragma unroll
    for (int nt = 0; nt < 4; ++nt) {
      int row = bm * 128 + wm + mt * 16 + quad * 4;
      int col = bn * 128 + wn + nt * 16 + l15;
#pragma unroll
      for (int r = 0; r < 4; ++r)
        C[(size_t)(row + r) * N + col] = acc[mt][nt][r] * scale;
    }
}

// ---------------- normalize + pack -----------------------------------------
__global__ __launch_bounds__(256) void normpack_kernel(
    const float* __restrict__ qkv_cls, const float* __restrict__ qkv_reg,
    uint16_t* __restrict__ Qc, uint16_t* __restrict__ Kc,
    uint16_t* __restrict__ Qr, uint16_t* __restrict__ Kr,
    uint16_t* __restrict__ Vt, uint16_t* __restrict__ Vcat,
    float* __restrict__ out) {
  __shared__ uint16_t vtile[64 * 136];
  int nt = blockIdx.x, h = blockIdx.y;
  int tid = threadIdx.x;
  int rl = tid >> 2, part = tid & 3;
  int n = nt * 64 + rl;
  int dbase = part * 32;
  size_t dsti = ((size_t)h * 2048 + n) * 128 + dbase;

#pragma unroll
  for (int tz = 0; tz < 4; ++tz) {
    const float* s;
    uint16_t* dst;
    if (tz == 0)      { s = qkv_cls + (size_t)n * 3072 + h * 128 + dbase;        dst = Qc + dsti; }
    else if (tz == 1) { s = qkv_cls + (size_t)n * 3072 + 1024 + h * 128 + dbase; dst = Kc + dsti; }
    else if (tz == 2) { s = qkv_reg + (size_t)n * 2048 + h * 128 + dbase;        dst = Qr + dsti; }
    else              { s = qkv_reg + (size_t)n * 2048 + 1024 + h * 128 + dbase; dst = Kr + dsti; }
    float v[32];
    float ssum = 0.f;
#pragma unroll
    for (int j = 0; j < 32; j += 4) {
      float4 t4 = *(const float4*)(s + j);
      v[j] = t4.x; v[j + 1] = t4.y; v[j + 2] = t4.z; v[j + 3] = t4.w;
      ssum += t4.x * t4.x + t4.y * t4.y + t4.z * t4.z + t4.w * t4.w;
    }
    ssum += __shfl_xor(ssum, 1);
    ssum += __shfl_xor(ssum, 2);
    float rn = rsqrtf(ssum);
#pragma unroll
    for (int j = 0; j < 32; j += 8) {
      U16x8 o;
#pragma unroll
      for (int q = 0; q < 8; ++q) o.u[q] = f2h(v[j + q] * rn);
      *(i32x4*)(dst + j) = o.v;
    }
  }
  // v path
  {
    const float* s = qkv_cls + (size_t)n * 3072 + 2048 + h * 128 + dbase;
    float v[32];
    float ssum = 0.f;
#pragma unroll
    for (int j = 0; j < 32; j += 4) {
      float4 t4 = *(const float4*)(s + j);
      v[j] = t4.x; v[j + 1] = t4.y; v[j + 2] = t4.z; v[j + 3] = t4.w;
      ssum += t4.x * t4.x + t4.y * t4.y + t4.z * t4.z + t4.w * t4.w;
      *(float4*)(out + (size_t)n * 2048 + 1024 + h * 128 + dbase + j) = t4;
    }
    ssum += __shfl_xor(ssum, 1);
    ssum += __shfl_xor(ssum, 2);
    float rn = rsqrtf(ssum);
#pragma unroll
    for (int j = 0; j < 32; j += 8) {
      U16x8 o;
#pragma unroll
      for (int q = 0; q < 8; ++q) o.u[q] = f2h(v[j + q] * rn);
      *(i32x4*)(Vcat + (size_t)n * 1024 + h * 128 + dbase + j) = o.v;
    }
#pragma unroll
    for (int j = 0; j < 32; ++j) vtile[rl * 136 + dbase + j] = f2h(v[j]);
  }
  __syncthreads();
#pragma unroll
  for (int i = 0; i < 32; ++i) {
    int flat = i * 256 + tid;
    int d = flat >> 6, c = flat & 63;
    Vt[((size_t)h * 128 + d) * 2048 + nt * 64 + c] = vtile[c * 136 + d];
  }
}

// ---------------- barrier-free per-wave flash attention ---------------------
// grid 1024 x 256. bx: h = bx&7 (XCD-aligned); rest=bx>>3: s=rest&1 (m-split),
// p=(rest>>1)&1 (0=cls,1=reg), q64=rest>>2. Wave w: 16 q-rows at q64*64+w*16.
// Each wave independent: K/V B-frags read directly from global (L2-resident).
// Partials: Opart f16 [p*2+s][2048][1024] unnormalized; Mpart/Lpart f32.
__global__ __launch_bounds__(256, 4) void attn_kernel(
    const uint16_t* __restrict__ Qc, const uint16_t* __restrict__ Kc,
    const uint16_t* __restrict__ Qr, const uint16_t* __restrict__ Kr,
    const uint16_t* __restrict__ Vt,
    const float* __restrict__ cls_score, const float* __restrict__ fg_score,
    uint16_t* __restrict__ Opart, float* __restrict__ Mpart,
    float* __restrict__ Lpart) {
  __shared__ __align__(16) uint16_t sP[4 * 640];  // per-wave 16x40 P tile

  int bx = blockIdx.x;
  int h = bx & 7;
  int rest = bx >> 3;
  int s_ = rest & 1;
  int p = (rest >> 1) & 1;
  int q64 = rest >> 2;
  int tid = threadIdx.x, w = tid >> 6, lane = tid & 63;
  int quad = lane >> 4, l15 = lane & 15;
  int qbase = q64 * 64 + w * 16;
  int mstart = s_ * 1024;
  uint16_t* Pb = sP + w * 640;

  const uint16_t* Qp = p ? Qr : Qc;
  const float* score = p ? fg_score : cls_score;
  const uint16_t* Kh = (p ? Kr : Kc) + (size_t)h * 2048 * 128;
  const uint16_t* Vh = Vt + (size_t)h * 128 * 2048;

  // Q fragments (held in registers for the whole kernel)
  f16x8 qf[4];
  const uint16_t* qp = Qp + ((size_t)h * 2048 + qbase + l15) * 128;
#pragma unroll
  for (int ks = 0; ks < 4; ++ks) qf[ks] = ldfrag(qp + ks * 32 + quad * 8);

  float sq[4];
#pragma unroll
  for (int r = 0; r < 4; ++r) sq[r] = score[qbase + quad * 4 + r] - 0.1f;

  float M[4], L[4];
  f32x4 O[8];
  f32x4 zero = {0.f, 0.f, 0.f, 0.f};
#pragma unroll
  for (int i = 0; i < 8; ++i) O[i] = zero;
#pragma unroll
  for (int r = 0; r < 4; ++r) { M[r] = -3.0e38f; L[r] = 0.f; }

  for (int it = 0; it < 32; ++it) {
    int m0 = mstart + it * 32;
    // score loads issued early so latency overlaps the QK MFMA chain
    float scm0 = score[m0 + l15];
    float scm1 = score[m0 + 16 + l15];

    // QK^T: 16 q-rows x 32 m-cols, B-frags straight from global (L2)
    const uint16_t* Kb = Kh + (size_t)m0 * 128;
    f32x4 S0 = zero, S1 = zero;
#pragma unroll
    for (int ks = 0; ks < 4; ++ks) {
      f16x8 b0 = ldfrag(Kb + (size_t)l15 * 128 + ks * 32 + quad * 8);
      f16x8 b1 = ldfrag(Kb + (size_t)(16 + l15) * 128 + ks * 32 + quad * 8);
      S0 = mfma16(qf[ks], b0, S0);
      S1 = mfma16(qf[ks], b1, S1);
    }

    // online softmax
    float l2[2][4];
    float sc20 = scm0 * (25.0f * K2E);
    float sc21 = scm1 * (25.0f * K2E);
#pragma unroll
    for (int r = 0; r < 4; ++r) {
      l2[0][r] = (scm0 > sq[r]) ? S0[r] * sc20 : 0.0f;
      l2[1][r] = (scm1 > sq[r]) ? S1[r] * sc21 : 0.0f;
    }
    float Mnew[4], alpha[4];
#pragma unroll
    for (int r = 0; r < 4; ++r) {
      float v = fmaxf(l2[0][r], l2[1][r]);
      v = fmaxf(v, __shfl_xor(v, 1));
      v = fmaxf(v, __shfl_xor(v, 2));
      v = fmaxf(v, __shfl_xor(v, 4));
      v = fmaxf(v, __shfl_xor(v, 8));
      Mnew[r] = fmaxf(M[r], v);
      alpha[r] = __builtin_amdgcn_exp2f(M[r] - Mnew[r]);
      M[r] = Mnew[r];
    }
#pragma unroll
    for (int r = 0; r < 4; ++r) {
      float s = 0.f;
#pragma unroll
      for (int mt = 0; mt < 2; ++mt) {
        float pe = __builtin_amdgcn_exp2f(l2[mt][r] - Mnew[r]);
        l2[mt][r] = pe;
        s += pe;
      }
      s += __shfl_xor(s, 1);
      s += __shfl_xor(s, 2);
      s += __shfl_xor(s, 4);
      s += __shfl_xor(s, 8);
      L[r] = L[r] * alpha[r] + s;
    }
#pragma unroll
    for (int dt = 0; dt < 8; ++dt)
#pragma unroll
      for (int r = 0; r < 4; ++r) O[dt][r] *= alpha[r];

    // P C-layout -> per-wave LDS -> A-layout frag (wave-synchronous, no barrier)
#pragma unroll
    for (int mt = 0; mt < 2; ++mt)
#pragma unroll
      for (int r = 0; r < 4; ++r)
        Pb[(quad * 4 + r) * 40 + mt * 16 + l15] = f2h(l2[mt][r]);
    f16x8 a = ldfrag(Pb + l15 * 40 + quad * 8);

    // PV: V^T B-frags straight from global (L2)
    const uint16_t* Vb = Vh + m0 + quad * 8;
#pragma unroll
    for (int dt = 0; dt < 8; ++dt) {
      f16x8 b = ldfrag(Vb + (size_t)(dt * 16 + l15) * 2048);
      O[dt] = mfma16(a, b, O[dt]);
    }
  }

  // epilogue: unnormalized O -> f16 partials, M/L -> f32
  int plane = p * 2 + s_;
  uint16_t* Op = Opart + (size_t)plane * 2097152;
#pragma unroll
  for (int dt = 0; dt < 8; ++dt)
#pragma unroll
    for (int r = 0; r < 4; ++r)
      Op[(size_t)(qbase + quad * 4 + r) * 1024 + h * 128 + dt * 16 + l15] =
          f2h(O[dt][r]);
  if (l15 == 0) {
#pragma unroll
    for (int r = 0; r < 4; ++r) {
      int qrow = qbase + quad * 4 + r;
      Mpart[((size_t)plane * 8 + h) * 2048 + qrow] = M[r];
      Lpart[((size_t)plane * 8 + h) * 2048 + qrow] = L[r];
    }
  }
}

// ---------------- combine splits+paths, write out + stats -------------------
__global__ __launch_bounds__(256) void combine_kernel(
    const uint16_t* __restrict__ Opart, const float* __restrict__ Mpart,
    const float* __restrict__ Lpart, float* __restrict__ out,
    float* __restrict__ stats) {
  int q = blockIdx.x;
  int t = threadIdx.x;
  int col = t * 4;
  int h = col >> 7;
  float res[4] = {0.f, 0.f, 0.f, 0.f};
#pragma unroll
  for (int p = 0; p < 2; ++p) {
    size_t i1 = ((size_t)(p * 2 + 0) * 8 + h) * 2048 + q;
    size_t i2 = ((size_t)(p * 2 + 1) * 8 + h) * 2048 + q;
    float M1 = Mpart[i1], M2 = Mpart[i2];
    float L1 = Lpart[i1], L2 = Lpart[i2];
    float Mx = fmaxf(M1, M2);
    float w1 = __builtin_amdgcn_exp2f(M1 - Mx);
    float w2 = __builtin_amdgcn_exp2f(M2 - Mx);
    float Lx = L1 * w1 + L2 * w2;
    float f1 = 0.5f * w1 / Lx, f2 = 0.5f * w2 / Lx;
    const uint16_t* O1 = Opart + (size_t)(p * 2 + 0) * 2097152 + (size_t)q * 1024 + col;
    const uint16_t* O2 = Opart + (size_t)(p * 2 + 1) * 2097152 + (size_t)q * 1024 + col;
    ushort4 a1 = *(const ushort4*)O1;
    ushort4 a2 = *(const ushort4*)O2;
    res[0] += h2f(a1.x) * f1 + h2f(a2.x) * f2;
    res[1] += h2f(a1.y) * f1 + h2f(a2.y) * f2;
    res[2] += h2f(a1.z) * f1 + h2f(a2.z) * f2;
    res[3] += h2f(a1.w) * f1 + h2f(a2.w) * f2;
  }
  float4 r4 = {res[0], res[1], res[2], res[3]};
  *(float4*)(out + (size_t)q * 2048 + col) = r4;
  if (t < 16) {
    int p = t >> 3, hh = t & 7;
    size_t i1 = ((size_t)(p * 2 + 0) * 8 + hh) * 2048 + q;
    size_t i2 = ((size_t)(p * 2 + 1) * 8 + hh) * 2048 + q;
    float M1 = Mpart[i1], M2 = Mpart[i2];
    float L1 = Lpart[i1], L2 = Lpart[i2];
    float Mx = fmaxf(M1, M2);
    float Lx = L1 * __builtin_amdgcn_exp2f(M1 - Mx) +
               L2 * __builtin_amdgcn_exp2f(M2 - Mx);
    stats[((size_t)(p * 2 + 0) * 8 + hh) * 2048 + q] = Mx;
    stats[((size_t)(p * 2 + 1) * 8 + hh) * 2048 + q] = Lx;
  }
}

// ---------------- sim_round2: masked-restricted softmax ---------------------
__global__ __launch_bounds__(256) void sim_kernel(
    const float* __restrict__ raw_mean,
    const uint16_t* __restrict__ Qc, const uint16_t* __restrict__ Kc,
    const uint16_t* __restrict__ Qr, const uint16_t* __restrict__ Kr,
    const float* __restrict__ cls_score, const float* __restrict__ fg_score,
    const float* __restrict__ stats, float* __restrict__ simout) {
  int n = blockIdx.x;
  int tid = threadIdx.x;
  __shared__ float red[4];
  __shared__ float s_inv;
  float e[8];
  float psum = 0.f;
  float cs_n = cls_score[n] - 0.1f, fs_n = fg_score[n] - 0.1f;
#pragma unroll
  for (int i = 0; i < 8; ++i) {
    int m = i * 256 + tid;
    float rm = raw_mean[(size_t)n * 2048 + m];
    float val = 0.f;
    if (rm > 0.75f) {
      float s = 0.f;
      float c2 = 25.0f * K2E * cls_score[m];
      float r2 = 25.0f * K2E * fg_score[m];
      float mc = (cls_score[m] > cs_n) ? 1.f : 0.f;
      float mr = (fg_score[m] > fs_n) ? 1.f : 0.f;
      for (int hh = 0; hh < 8; ++hh) {
        const uint16_t* qc = Qc + ((size_t)hh * 2048 + n) * 128;
        const uint16_t* kc = Kc + ((size_t)hh * 2048 + m) * 128;
        const uint16_t* qr = Qr + ((size_t)hh * 2048 + n) * 128;
        const uint16_t* kr = Kr + ((size_t)hh * 2048 + m) * 128;
        float dc = 0.f, dr = 0.f;
        for (int d = 0; d < 128; ++d) {
          dc += h2f(qc[d]) * h2f(kc[d]);
          dr += h2f(qr[d]) * h2f(kr[d]);
        }
        float lc = dc * c2 * mc;
        float lr = dr * r2 * mr;
        float ac = __builtin_amdgcn_exp2f(lc - stats[((size_t)0 * 8 + hh) * 2048 + n]) /
                   stats[((size_t)1 * 8 + hh) * 2048 + n];
        float ar = __builtin_amdgcn_exp2f(lr - stats[((size_t)2 * 8 + hh) * 2048 + n]) /
                   stats[((size_t)3 * 8 + hh) * 2048 + n];
        s += ac + ar;
      }
      s *= (1.0f / 16.0f);
      val = __builtin_amdgcn_exp2f(s * K2E);  // e^s
    }
    e[i] = val;
    psum += val;
  }
  for (int off = 1; off < 64; off <<= 1) psum += __shfl_xor(psum, off);
  if ((tid & 63) == 0) red[tid >> 6] = psum;
  __syncthreads();
  if (tid == 0) s_inv = 1.0f / (red[0] + red[1] + red[2] + red[3]);
  __syncthreads();
  float inv = s_inv;
#pragma unroll
  for (int i = 0; i < 8; ++i)
    simout[(size_t)n * 2048 + i * 256 + tid] = e[i] * inv;
}

// ---------------- host launch ------------------------------------------------
extern "C" void kernel_launch(void* const* d_in, const int* in_sizes, int n_in,
                              void* d_out, int out_size, void* d_ws, size_t ws_size,
                              hipStream_t stream) {
  const float* x_cls = (const float*)d_in[0];
  const float* x_reg = (const float*)d_in[1];
  const float* cls_score = (const float*)d_in[2];
  const float* fg_score = (const float*)d_in[3];
  const float* W_cls = (const float*)d_in[4];
  const float* W_reg = (const float*)d_in[5];
  float* out = (float*)d_out;
  char* ws = (char*)d_ws;

  const size_t OFF_XC   = 0;
  const size_t OFF_XR   = OFF_XC + 4194304;
  const size_t OFF_WTC  = OFF_XR + 4194304;
  const size_t OFF_WTR  = OFF_WTC + 6291456;
  const size_t OFF_QC   = OFF_WTR + 4194304;
  const size_t OFF_KC   = OFF_QC + 4194304;
  const size_t OFF_QR   = OFF_KC + 4194304;
  const size_t OFF_KR   = OFF_QR + 4194304;
  const size_t OFF_VT   = OFF_KR + 4194304;
  const size_t OFF_VCAT = OFF_VT + 4194304;
  const size_t OFF_STAT = OFF_VCAT + 4194304;
  const size_t OFF_QKVC = OFF_STAT + 262144;
  const size_t OFF_QKVR = OFF_QKVC + 25165824;
  const size_t OFF_RAW  = OFF_QKVC;              // raw_mean aliases dead qkv_cls
  const size_t OFF_OP   = OFF_QKVR;              // Opart f16 16MB over dead qkv_reg
  const size_t OFF_MP   = OFF_QKVC + 16777216;   // Mpart in qkv_cls tail hole
  const size_t OFF_LP   = OFF_MP + 262144;

  uint16_t* xc_b = (uint16_t*)(ws + OFF_XC);
  uint16_t* xr_b = (uint16_t*)(ws + OFF_XR);
  uint16_t* Wtc  = (uint16_t*)(ws + OFF_WTC);
  uint16_t* Wtr  = (uint16_t*)(ws + OFF_WTR);
  uint16_t* Qc   = (uint16_t*)(ws + OFF_QC);
  uint16_t* Kc   = (uint16_t*)(ws + OFF_KC);
  uint16_t* Qr   = (uint16_t*)(ws + OFF_QR);
  uint16_t* Kr   = (uint16_t*)(ws + OFF_KR);
  uint16_t* Vt   = (uint16_t*)(ws + OFF_VT);
  uint16_t* Vcat = (uint16_t*)(ws + OFF_VCAT);
  float* stats   = (float*)(ws + OFF_STAT);
  float* qkvc    = (float*)(ws + OFF_QKVC);
  float* qkvr    = (float*)(ws + OFF_QKVR);
  float* rawm    = (float*)(ws + OFF_RAW);
  uint16_t* Opart = (uint16_t*)(ws + OFF_OP);
  float* Mpart   = (float*)(ws + OFF_MP);
  float* Lpart   = (float*)(ws + OFF_LP);

  cast_f16_kernel<<<1024, 256, 0, stream>>>(x_cls, xc_b, 262144);
  cast_f16_kernel<<<1024, 256, 0, stream>>>(x_reg, xr_b, 262144);
  transpose_cast_kernel<<<dim3(16, 48), 256, 0, stream>>>(W_cls, Wtc, 3072);
  transpose_cast_kernel<<<dim3(16, 32), 256, 0, stream>>>(W_reg, Wtr, 3072);
  gemm_bt_kernel<<<dim3(16, 24), 256, 0, stream>>>(xc_b, Wtc, qkvc, 3072, 1024, 1.0f);
  gemm_bt_kernel<<<dim3(16, 16), 256, 0, stream>>>(xr_b, Wtr, qkvr, 2048, 1024, 1.0f);
  normpack_kernel<<<dim3(32, 8), 256, 0, stream>>>(qkvc, qkvr, Qc, Kc, Qr, Kr, Vt, Vcat, out);
  gemm_bt_kernel<<<dim3(16, 16), 256, 0, stream>>>(Vcat, Vcat, rawm, 2048, 1024, 0.125f);
  attn_kernel<<<1024, 256, 0, stream>>>(Qc, Kc, Qr, Kr, Vt, cls_score, fg_score,
                                        Opart, Mpart, Lpart);
  combine_kernel<<<2048, 256, 0, stream>>>(Opart, Mpart, Lpart, out, stats);
  sim_kernel<<<2048, 256, 0, stream>>>(rawm, Qc, Kc, Qr, Kr, cls_score, fg_score,
                                       stats, out + 4194304);
}

// Round 5
// 336.254 us; speedup vs baseline: 1.4460x; 1.4460x over previous
//
#include <hip/hip_runtime.h>
#include <stdint.h>
#include <stddef.h>

#define DEV __device__ __forceinline__

typedef _Float16 f16x8 __attribute__((ext_vector_type(8)));
typedef float    f32x4 __attribute__((ext_vector_type(4)));
typedef int      i32x4 __attribute__((ext_vector_type(4)));

#define K2E 1.44269504088896340736f
#define SC25 (25.0f * K2E)

DEV uint16_t f2h(float f) {
  _Float16 h = (_Float16)f;
  return __builtin_bit_cast(uint16_t, h);
}
DEV float h2f(uint16_t u) {
  return (float)__builtin_bit_cast(_Float16, u);
}
DEV f16x8 ldfrag(const uint16_t* p) {
  i32x4 v = *(const i32x4*)p;
  return __builtin_bit_cast(f16x8, v);
}
DEV f32x4 mfma16(f16x8 a, f16x8 b, f32x4 c) {
  return __builtin_amdgcn_mfma_f32_16x16x32_f16(a, b, c, 0, 0, 0);
}
// async global->LDS: each lane copies 16B; LDS dest = base + lane*16
DEV void gld_lds16(const uint16_t* g, uint16_t* l) {
  __builtin_amdgcn_global_load_lds(
      (__attribute__((address_space(1))) void*)g,
      (__attribute__((address_space(3))) void*)l, 16, 0, 0);
}

union U16x8 { uint16_t u[8]; i32x4 v; };

// ---------------- fused prep: casts + weight transposes ---------------------
// b<1024: cast x_cls; b<2048: cast x_reg; b<2816: transpose W_cls (16x48);
// else transpose W_reg (16x32). Both W are [1024][3072] f32; reg uses q,k only.
__global__ __launch_bounds__(256) void prep_kernel(
    const float* __restrict__ x_cls, const float* __restrict__ x_reg,
    const float* __restrict__ W_cls, const float* __restrict__ W_reg,
    uint16_t* __restrict__ xc_b, uint16_t* __restrict__ xr_b,
    uint16_t* __restrict__ Wtc, uint16_t* __restrict__ Wtr) {
  __shared__ float tile[64][65];
  int b = blockIdx.x, tid = threadIdx.x;
  if (b < 2048) {
    const float* in = (b < 1024) ? x_cls : x_reg;
    uint16_t* outp = (b < 1024) ? xc_b : xr_b;
    int i = (b & 1023) * 256 + tid;
    float4 a = *(const float4*)(in + (size_t)i * 8);
    float4 c = *(const float4*)(in + (size_t)i * 8 + 4);
    U16x8 r;
    r.u[0] = f2h(a.x); r.u[1] = f2h(a.y); r.u[2] = f2h(a.z); r.u[3] = f2h(a.w);
    r.u[4] = f2h(c.x); r.u[5] = f2h(c.y); r.u[6] = f2h(c.z); r.u[7] = f2h(c.w);
    *(i32x4*)(outp + (size_t)i * 8) = r.v;
    return;
  }
  const float* W;
  uint16_t* Wt;
  int idx;
  if (b < 2816) { W = W_cls; Wt = Wtc; idx = b - 2048; }
  else          { W = W_reg; Wt = Wtr; idx = b - 2816; }
  int k0 = (idx & 15) * 64;
  int n0 = (idx >> 4) * 64;
#pragma unroll
  for (int i = 0; i < 16; ++i) {
    int flat = i * 256 + tid;
    int r = flat >> 6, c = flat & 63;
    tile[r][c] = W[(size_t)(k0 + r) * 3072 + n0 + c];
  }
  __syncthreads();
#pragma unroll
  for (int i = 0; i < 16; ++i) {
    int flat = i * 256 + tid;
    int r = flat >> 6, c = flat & 63;
    Wt[(size_t)(n0 + r) * 1024 + k0 + c] = f2h(tile[c][r]);
  }
}

// ---------------- GEMM body: C[M,N] = A[M,K] @ Bt[N,K]^T --------------------
// 128x128 tile, BK=64, global_load_lds w16, XOR k-seg swizzle (conflict-free)
DEV void gemm_body(const uint16_t* __restrict__ A, const uint16_t* __restrict__ Bt,
                   float* __restrict__ C, int N, int K, float scale,
                   int bm, int bn) {
  __shared__ __align__(16) uint16_t As[128 * 64];
  __shared__ __align__(16) uint16_t Bs[128 * 64];
  int tid = threadIdx.x;
  int w = tid >> 6, lane = tid & 63, quad = lane >> 4, l15 = lane & 15;
  int wm = (w >> 1) * 64, wn = (w & 1) * 64;
  const uint16_t* Arow = A + (size_t)(bm * 128) * K;
  const uint16_t* Brow = Bt + (size_t)(bn * 128) * K;
  f32x4 acc[4][4];
  f32x4 zero = {0.f, 0.f, 0.f, 0.f};
#pragma unroll
  for (int i = 0; i < 4; ++i)
#pragma unroll
    for (int j = 0; j < 4; ++j) acc[i][j] = zero;
  int rl = lane >> 3, cl = lane & 7;
  int sw = l15 & 7;
  for (int k0 = 0; k0 < K; k0 += 64) {
    __syncthreads();
#pragma unroll
    for (int t = 0; t < 4; ++t) {
      int r0 = w * 32 + t * 8;
      gld_lds16(Arow + (size_t)(r0 + rl) * K + k0 + ((cl ^ rl) << 3), As + r0 * 64);
      gld_lds16(Brow + (size_t)(r0 + rl) * K + k0 + ((cl ^ rl) << 3), Bs + r0 * 64);
    }
    __syncthreads();
#pragma unroll
    for (int ks = 0; ks < 2; ++ks) {
      f16x8 af[4], bf[4];
#pragma unroll
      for (int mt = 0; mt < 4; ++mt)
        af[mt] = ldfrag(As + (wm + mt * 16 + l15) * 64 + ((((ks << 2) + quad) ^ sw) << 3));
#pragma unroll
      for (int nt = 0; nt < 4; ++nt)
        bf[nt] = ldfrag(Bs + (wn + nt * 16 + l15) * 64 + ((((ks << 2) + quad) ^ sw) << 3));
#pragma unroll
      for (int mt = 0; mt < 4; ++mt)
#pragma unroll
        for (int nt = 0; nt < 4; ++nt)
          acc[mt][nt] = mfma16(af[mt], bf[nt], acc[mt][nt]);
    }
  }
#pragma unroll
  for (int mt = 0; mt < 4; ++mt)
#pragma unroll
    for (int nt = 0; nt < 4; ++nt) {
      int row = bm * 128 + wm + mt * 16 + quad * 4;
      int col = bn * 128 + wn + nt * 16 + l15;
#pragma unroll
      for (int r = 0; r < 4; ++r)
        C[(size_t)(row + r) * N + col] = acc[mt][nt][r] * scale;
    }
}

// fused QKV GEMMs: by<24 -> cls (N=3072), else reg (N=2048)
__global__ __launch_bounds__(256, 2) void gemm_qkv_kernel(
    const uint16_t* __restrict__ xc, const uint16_t* __restrict__ Wtc,
    float* __restrict__ qkvc, const uint16_t* __restrict__ xr,
    const uint16_t* __restrict__ Wtr, float* __restrict__ qkvr) {
  if (blockIdx.y < 24)
    gemm_body(xc, Wtc, qkvc, 3072, 1024, 1.0f, blockIdx.x, blockIdx.y);
  else
    gemm_body(xr, Wtr, qkvr, 2048, 1024, 1.0f, blockIdx.x, blockIdx.y - 24);
}

__global__ __launch_bounds__(256, 2) void gemm_raw_kernel(
    const uint16_t* __restrict__ Vcat, float* __restrict__ rawm) {
  gemm_body(Vcat, Vcat, rawm, 2048, 1024, 0.125f, blockIdx.x, blockIdx.y);
}

// ---------------- normalize + pack -----------------------------------------
__global__ __launch_bounds__(256) void normpack_kernel(
    const float* __restrict__ qkv_cls, const float* __restrict__ qkv_reg,
    uint16_t* __restrict__ Qc, uint16_t* __restrict__ Kc,
    uint16_t* __restrict__ Qr, uint16_t* __restrict__ Kr,
    uint16_t* __restrict__ Vt, uint16_t* __restrict__ Vcat,
    float* __restrict__ out) {
  __shared__ uint16_t vtile[64 * 136];
  int nt = blockIdx.x, h = blockIdx.y;
  int tid = threadIdx.x;
  int rl = tid >> 2, part = tid & 3;
  int n = nt * 64 + rl;
  int dbase = part * 32;
  size_t dsti = ((size_t)h * 2048 + n) * 128 + dbase;

#pragma unroll
  for (int tz = 0; tz < 4; ++tz) {
    const float* s;
    uint16_t* dst;
    if (tz == 0)      { s = qkv_cls + (size_t)n * 3072 + h * 128 + dbase;        dst = Qc + dsti; }
    else if (tz == 1) { s = qkv_cls + (size_t)n * 3072 + 1024 + h * 128 + dbase; dst = Kc + dsti; }
    else if (tz == 2) { s = qkv_reg + (size_t)n * 2048 + h * 128 + dbase;        dst = Qr + dsti; }
    else              { s = qkv_reg + (size_t)n * 2048 + 1024 + h * 128 + dbase; dst = Kr + dsti; }
    float v[32];
    float ssum = 0.f;
#pragma unroll
    for (int j = 0; j < 32; j += 4) {
      float4 t4 = *(const float4*)(s + j);
      v[j] = t4.x; v[j + 1] = t4.y; v[j + 2] = t4.z; v[j + 3] = t4.w;
      ssum += t4.x * t4.x + t4.y * t4.y + t4.z * t4.z + t4.w * t4.w;
    }
    ssum += __shfl_xor(ssum, 1);
    ssum += __shfl_xor(ssum, 2);
    float rn = rsqrtf(ssum);
#pragma unroll
    for (int j = 0; j < 32; j += 8) {
      U16x8 o;
#pragma unroll
      for (int q = 0; q < 8; ++q) o.u[q] = f2h(v[j + q] * rn);
      *(i32x4*)(dst + j) = o.v;
    }
  }
  // v path
  {
    const float* s = qkv_cls + (size_t)n * 3072 + 2048 + h * 128 + dbase;
    float v[32];
    float ssum = 0.f;
#pragma unroll
    for (int j = 0; j < 32; j += 4) {
      float4 t4 = *(const float4*)(s + j);
      v[j] = t4.x; v[j + 1] = t4.y; v[j + 2] = t4.z; v[j + 3] = t4.w;
      ssum += t4.x * t4.x + t4.y * t4.y + t4.z * t4.z + t4.w * t4.w;
      *(float4*)(out + (size_t)n * 2048 + 1024 + h * 128 + dbase + j) = t4;
    }
    ssum += __shfl_xor(ssum, 1);
    ssum += __shfl_xor(ssum, 2);
    float rn = rsqrtf(ssum);
#pragma unroll
    for (int j = 0; j < 32; j += 8) {
      U16x8 o;
#pragma unroll
      for (int q = 0; q < 8; ++q) o.u[q] = f2h(v[j + q] * rn);
      *(i32x4*)(Vcat + (size_t)n * 1024 + h * 128 + dbase + j) = o.v;
    }
#pragma unroll
    for (int j = 0; j < 32; ++j) vtile[rl * 136 + dbase + j] = f2h(v[j]);
  }
  __syncthreads();
#pragma unroll
  for (int i = 0; i < 32; ++i) {
    int flat = i * 256 + tid;
    int d = flat >> 6, c = flat & 63;
    Vt[((size_t)h * 128 + d) * 2048 + nt * 64 + c] = vtile[c * 136 + d];
  }
}

// ---------------- flash attention: 1 path/block, m-split=2 ------------------
// grid 1024: h=bx&7; rest=bx>>3: s=rest&1, p=(rest>>1)&1, q64=rest>>2 (32).
// Block: 64 q-rows (wave w -> 16 rows), Bk=64, 16 m-iters over its half.
// LDS 40960B exactly -> 4 blocks/CU. XOR-swizzled unpadded staging via
// global_load_lds w16; all b128 frag reads <=2-way banks (free).
__global__ __launch_bounds__(256, 4) void attn_kernel(
    const uint16_t* __restrict__ Qc, const uint16_t* __restrict__ Kc,
    const uint16_t* __restrict__ Qr, const uint16_t* __restrict__ Kr,
    const uint16_t* __restrict__ Vt,
    const float* __restrict__ cls_score, const float* __restrict__ fg_score,
    uint16_t* __restrict__ Opart, float* __restrict__ Mpart,
    float* __restrict__ Lpart) {
  __shared__ __align__(16) uint16_t sK[64 * 128];    // 16 KB
  __shared__ __align__(16) uint16_t sVt[128 * 64];   // 16 KB
  __shared__ __align__(16) uint16_t sP[4 * 16 * 64]; // 8 KB (per-wave 16x64)

  int bx = blockIdx.x;
  int h = bx & 7;
  int rest = bx >> 3;
  int s_ = rest & 1;
  int p = (rest >> 1) & 1;
  int q64 = rest >> 2;
  int tid = threadIdx.x, w = tid >> 6, lane = tid & 63;
  int quad = lane >> 4, l15 = lane & 15;
  int qbase = q64 * 64 + w * 16;
  int mstart = s_ * 1024;
  uint16_t* Pb = sP + w * 1024;

  const uint16_t* Qp = p ? Qr : Qc;
  const float* score = p ? fg_score : cls_score;
  const uint16_t* Kh = (p ? Kr : Kc) + (size_t)h * 2048 * 128;
  const uint16_t* Vh = Vt + (size_t)h * 128 * 2048;

  f16x8 qf[4];
  const uint16_t* qp = Qp + ((size_t)h * 2048 + qbase + l15) * 128;
#pragma unroll
  for (int ks = 0; ks < 4; ++ks) qf[ks] = ldfrag(qp + ks * 32 + quad * 8);

  float sq[4];
#pragma unroll
  for (int r = 0; r < 4; ++r) sq[r] = score[qbase + quad * 4 + r] - 0.1f;

  float M[4], Lacc[4];
  f32x4 O[8];
  f32x4 zero = {0.f, 0.f, 0.f, 0.f};
#pragma unroll
  for (int i = 0; i < 8; ++i) O[i] = zero;
#pragma unroll
  for (int r = 0; r < 4; ++r) { M[r] = -3.0e38f; Lacc[r] = 0.f; }

  int krl = lane >> 4, kcl = lane & 15;  // K stage: 4 rows x 16 segs/instr
  int vrl = lane >> 3, vcl = lane & 7;   // V stage: 8 rows x 8 segs/instr
  int xk = l15 & 7;

  for (int it = 0; it < 16; ++it) {
    int m0 = mstart + it * 64;
    __syncthreads();
#pragma unroll
    for (int t = 0; t < 4; ++t) {
      int r0 = w * 16 + t * 4;
      int key = (t * 4 + krl) & 7;
      gld_lds16(Kh + (size_t)(m0 + r0 + krl) * 128 + ((kcl ^ key) << 3),
                sK + r0 * 128);
    }
#pragma unroll
    for (int t = 0; t < 4; ++t) {
      int d0 = w * 32 + t * 8;
      gld_lds16(Vh + (size_t)(d0 + vrl) * 2048 + m0 + ((vcl ^ vrl) << 3),
                sVt + d0 * 64);
    }
    __syncthreads();

    // QK^T: 16 q-rows x 64 m-cols
    f32x4 S[4];
#pragma unroll
    for (int mt = 0; mt < 4; ++mt) S[mt] = zero;
#pragma unroll
    for (int ks = 0; ks < 4; ++ks)
#pragma unroll
      for (int mt = 0; mt < 4; ++mt) {
        f16x8 b = ldfrag(sK + (mt * 16 + l15) * 128 + (((ks * 4 + quad) ^ xk) << 3));
        S[mt] = mfma16(qf[ks], b, S[mt]);
      }

    // online softmax (per-lane L accumulation; cross-lane reduce deferred)
    float l2[4][4];
#pragma unroll
    for (int mt = 0; mt < 4; ++mt) {
      float scm = score[m0 + mt * 16 + l15];
      float sc2 = scm * SC25;
#pragma unroll
      for (int r = 0; r < 4; ++r)
        l2[mt][r] = (scm > sq[r]) ? S[mt][r] * sc2 : 0.0f;
    }
    float Mnew[4], alpha[4];
#pragma unroll
    for (int r = 0; r < 4; ++r) {
      float v = fmaxf(fmaxf(l2[0][r], l2[1][r]), fmaxf(l2[2][r], l2[3][r]));
      v = fmaxf(v, __shfl_xor(v, 1));
      v = fmaxf(v, __shfl_xor(v, 2));
      v = fmaxf(v, __shfl_xor(v, 4));
      v = fmaxf(v, __shfl_xor(v, 8));
      Mnew[r] = fmaxf(M[r], v);
      alpha[r] = __builtin_amdgcn_exp2f(M[r] - Mnew[r]);
      M[r] = Mnew[r];
    }
#pragma unroll
    for (int r = 0; r < 4; ++r) {
      float ssum = 0.f;
#pragma unroll
      for (int mt = 0; mt < 4; ++mt) {
        float pe = __builtin_amdgcn_exp2f(l2[mt][r] - Mnew[r]);
        l2[mt][r] = pe;
        ssum += pe;
      }
      Lacc[r] = Lacc[r] * alpha[r] + ssum;
    }
#pragma unroll
    for (int dt = 0; dt < 8; ++dt)
#pragma unroll
      for (int r = 0; r < 4; ++r) O[dt][r] *= alpha[r];

    // P C-layout -> per-wave LDS (XOR-swizzled), wave-internal RAW (in-order)
#pragma unroll
    for (int mt = 0; mt < 4; ++mt) {
      int seg = mt * 2 + (l15 >> 3);
#pragma unroll
      for (int r = 0; r < 4; ++r) {
        int row = quad * 4 + r;
        Pb[row * 64 + ((seg ^ (row & 7)) << 3) + (l15 & 7)] = f2h(l2[mt][r]);
      }
    }
    // PV
#pragma unroll
    for (int ks2 = 0; ks2 < 2; ++ks2) {
      f16x8 a = ldfrag(Pb + l15 * 64 + (((ks2 * 4 + quad) ^ xk) << 3));
#pragma unroll
      for (int dt = 0; dt < 8; ++dt) {
        f16x8 b = ldfrag(sVt + (dt * 16 + l15) * 64 + (((ks2 * 4 + quad) ^ xk) << 3));
        O[dt] = mfma16(a, b, O[dt]);
      }
    }
  }

  // final cross-lane L reduce + partial writeback
  float L[4];
#pragma unroll
  for (int r = 0; r < 4; ++r) {
    float s = Lacc[r];
    s += __shfl_xor(s, 1);
    s += __shfl_xor(s, 2);
    s += __shfl_xor(s, 4);
    s += __shfl_xor(s, 8);
    L[r] = s;
  }
  int plane = p * 2 + s_;
  uint16_t* Op = Opart + (size_t)plane * 2097152;
#pragma unroll
  for (int dt = 0; dt < 8; ++dt)
#pragma unroll
    for (int r = 0; r < 4; ++r)
      Op[(size_t)(qbase + quad * 4 + r) * 1024 + h * 128 + dt * 16 + l15] =
          f2h(O[dt][r]);
  if (l15 == 0) {
#pragma unroll
    for (int r = 0; r < 4; ++r) {
      int qrow = qbase + quad * 4 + r;
      Mpart[((size_t)plane * 8 + h) * 2048 + qrow] = M[r];
      Lpart[((size_t)plane * 8 + h) * 2048 + qrow] = L[r];
    }
  }
}

// ---------------- fused combine + sim_round2 --------------------------------
__global__ __launch_bounds__(256) void combine_sim_kernel(
    const uint16_t* __restrict__ Opart, const float* __restrict__ Mpart,
    const float* __restrict__ Lpart, const float* __restrict__ raw_mean,
    const uint16_t* __restrict__ Qc, const uint16_t* __restrict__ Kc,
    const uint16_t* __restrict__ Qr, const uint16_t* __restrict__ Kr,
    const float* __restrict__ cls_score, const float* __restrict__ fg_score,
    float* __restrict__ out, float* __restrict__ simout) {
  int n = blockIdx.x;
  int t = threadIdx.x;
  __shared__ float sM[2][8], sL[2][8];
  __shared__ float red[4];
  __shared__ float s_inv;
  if (t < 16) {
    int p = t >> 3, hh = t & 7;
    size_t i1 = ((size_t)(p * 2 + 0) * 8 + hh) * 2048 + n;
    size_t i2 = ((size_t)(p * 2 + 1) * 8 + hh) * 2048 + n;
    float M1 = Mpart[i1], M2 = Mpart[i2];
    float L1 = Lpart[i1], L2 = Lpart[i2];
    float Mx = fmaxf(M1, M2);
    float Lx = L1 * __builtin_amdgcn_exp2f(M1 - Mx) +
               L2 * __builtin_amdgcn_exp2f(M2 - Mx);
    sM[p][hh] = Mx;
    sL[p][hh] = Lx;
  }
  __syncthreads();

  // combine partials -> out row n (first 1024 cols)
  {
    int col = t * 4;
    int h = col >> 7;
    float res[4] = {0.f, 0.f, 0.f, 0.f};
#pragma unroll
    for (int p = 0; p < 2; ++p) {
      size_t i1 = ((size_t)(p * 2 + 0) * 8 + h) * 2048 + n;
      size_t i2 = ((size_t)(p * 2 + 1) * 8 + h) * 2048 + n;
      float Mx = sM[p][h];
      float iLx = 0.5f / sL[p][h];
      float f1 = __builtin_amdgcn_exp2f(Mpart[i1] - Mx) * iLx;
      float f2 = __builtin_amdgcn_exp2f(Mpart[i2] - Mx) * iLx;
      const uint16_t* O1 = Opart + (size_t)(p * 2 + 0) * 2097152 + (size_t)n * 1024 + col;
      const uint16_t* O2 = Opart + (size_t)(p * 2 + 1) * 2097152 + (size_t)n * 1024 + col;
      ushort4 a1 = *(const ushort4*)O1;
      ushort4 a2 = *(const ushort4*)O2;
      res[0] += h2f(a1.x) * f1 + h2f(a2.x) * f2;
      res[1] += h2f(a1.y) * f1 + h2f(a2.y) * f2;
      res[2] += h2f(a1.z) * f1 + h2f(a2.z) * f2;
      res[3] += h2f(a1.w) * f1 + h2f(a2.w) * f2;
    }
    float4 r4 = {res[0], res[1], res[2], res[3]};
    *(float4*)(out + (size_t)n * 2048 + col) = r4;
  }

  // sim_round2: masked-restricted softmax over row n
  float e[8];
  float psum = 0.f;
  float cs_n = cls_score[n] - 0.1f, fs_n = fg_score[n] - 0.1f;
#pragma unroll
  for (int i = 0; i < 8; ++i) {
    int m = i * 256 + t;
    float rm = raw_mean[(size_t)n * 2048 + m];
    float val = 0.f;
    if (rm > 0.75f) {
      float s = 0.f;
      float c2 = SC25 * cls_score[m];
      float r2 = SC25 * fg_score[m];
      float mc = (cls_score[m] > cs_n) ? 1.f : 0.f;
      float mr = (fg_score[m] > fs_n) ? 1.f : 0.f;
      for (int hh = 0; hh < 8; ++hh) {
        const uint16_t* qc = Qc + ((size_t)hh * 2048 + n) * 128;
        const uint16_t* kc = Kc + ((size_t)hh * 2048 + m) * 128;
        const uint16_t* qr = Qr + ((size_t)hh * 2048 + n) * 128;
        const uint16_t* kr = Kr + ((size_t)hh * 2048 + m) * 128;
        float dc = 0.f, dr = 0.f;
        for (int d = 0; d < 128; ++d) {
          dc += h2f(qc[d]) * h2f(kc[d]);
          dr += h2f(qr[d]) * h2f(kr[d]);
        }
        float lc = dc * c2 * mc;
        float lr = dr * r2 * mr;
        float ac = __builtin_amdgcn_exp2f(lc - sM[0][hh]) / sL[0][hh];
        float ar = __builtin_amdgcn_exp2f(lr - sM[1][hh]) / sL[1][hh];
        s += ac + ar;
      }
      s *= (1.0f / 16.0f);
      val = __builtin_amdgcn_exp2f(s * K2E);  // e^s
    }
    e[i] = val;
    psum += val;
  }
  for (int off = 1; off < 64; off <<= 1) psum += __shfl_xor(psum, off);
  if ((t & 63) == 0) red[t >> 6] = psum;
  __syncthreads();
  if (t == 0) s_inv = 1.0f / (red[0] + red[1] + red[2] + red[3]);
  __syncthreads();
  float inv = s_inv;
#pragma unroll
  for (int i = 0; i < 8; ++i)
    simout[(size_t)n * 2048 + i * 256 + t] = e[i] * inv;
}

// ---------------- host launch ------------------------------------------------
extern "C" void kernel_launch(void* const* d_in, const int* in_sizes, int n_in,
                              void* d_out, int out_size, void* d_ws, size_t ws_size,
                              hipStream_t stream) {
  const float* x_cls = (const float*)d_in[0];
  const float* x_reg = (const float*)d_in[1];
  const float* cls_score = (const float*)d_in[2];
  const float* fg_score = (const float*)d_in[3];
  const float* W_cls = (const float*)d_in[4];
  const float* W_reg = (const float*)d_in[5];
  float* out = (float*)d_out;
  char* ws = (char*)d_ws;

  const size_t OFF_XC   = 0;
  const size_t OFF_XR   = OFF_XC + 4194304;
  const size_t OFF_WTC  = OFF_XR + 4194304;
  const size_t OFF_WTR  = OFF_WTC + 6291456;
  const size_t OFF_QC   = OFF_WTR + 4194304;
  const size_t OFF_KC   = OFF_QC + 4194304;
  const size_t OFF_QR   = OFF_KC + 4194304;
  const size_t OFF_KR   = OFF_QR + 4194304;
  const size_t OFF_VT   = OFF_KR + 4194304;
  const size_t OFF_VCAT = OFF_VT + 4194304;
  const size_t OFF_STAT = OFF_VCAT + 4194304;
  const size_t OFF_QKVC = OFF_STAT + 262144;
  const size_t OFF_QKVR = OFF_QKVC + 25165824;
  const size_t OFF_RAW  = OFF_QKVC;              // raw_mean aliases dead qkv_cls
  const size_t OFF_OP   = OFF_QKVR;              // Opart f16 16MB over dead qkv_reg
  const size_t OFF_MP   = OFF_QKVC + 16777216;   // Mpart in qkv_cls tail hole
  const size_t OFF_LP   = OFF_MP + 262144;

  uint16_t* xc_b = (uint16_t*)(ws + OFF_XC);
  uint16_t* xr_b = (uint16_t*)(ws + OFF_XR);
  uint16_t* Wtc  = (uint16_t*)(ws + OFF_WTC);
  uint16_t* Wtr  = (uint16_t*)(ws + OFF_WTR);
  uint16_t* Qc   = (uint16_t*)(ws + OFF_QC);
  uint16_t* Kc   = (uint16_t*)(ws + OFF_KC);
  uint16_t* Qr   = (uint16_t*)(ws + OFF_QR);
  uint16_t* Kr   = (uint16_t*)(ws + OFF_KR);
  uint16_t* Vt   = (uint16_t*)(ws + OFF_VT);
  uint16_t* Vcat = (uint16_t*)(ws + OFF_VCAT);
  float* qkvc    = (float*)(ws + OFF_QKVC);
  float* qkvr    = (float*)(ws + OFF_QKVR);
  float* rawm    = (float*)(ws + OFF_RAW);
  uint16_t* Opart = (uint16_t*)(ws + OFF_OP);
  float* Mpart   = (float*)(ws + OFF_MP);
  float* Lpart   = (float*)(ws + OFF_LP);

  prep_kernel<<<3328, 256, 0, stream>>>(x_cls, x_reg, W_cls, W_reg,
                                        xc_b, xr_b, Wtc, Wtr);
  gemm_qkv_kernel<<<dim3(16, 40), 256, 0, stream>>>(xc_b, Wtc, qkvc,
                                                    xr_b, Wtr, qkvr);
  normpack_kernel<<<dim3(32, 8), 256, 0, stream>>>(qkvc, qkvr, Qc, Kc, Qr, Kr,
                                                   Vt, Vcat, out);
  gemm_raw_kernel<<<dim3(16, 16), 256, 0, stream>>>(Vcat, rawm);
  attn_kernel<<<1024, 256, 0, stream>>>(Qc, Kc, Qr, Kr, Vt, cls_score, fg_score,
                                        Opart, Mpart, Lpart);
  combine_sim_kernel<<<2048, 256, 0, stream>>>(Opart, Mpart, Lpart, rawm,
                                               Qc, Kc, Qr, Kr, cls_score,
                                               fg_score, out, out + 4194304);
}